// Round 1
// baseline (228.586 us; speedup 1.0000x reference)
//
#include <hip/hip_runtime.h>
#include <hip/hip_bf16.h>

// CouplingSplineLayer fused kernel for MI355X (gfx950), round 9.
// R9 = R8 with G1+G2 converted to mfma_f32_32x32x16_bf16 (higher FLOP/cyc,
// half the MFMA issue slots, G1 K-pad 32->16) and bias folded into the MFMA
// C-operand for all three GEMMs (kills 4 v_add_f32 per store). G3 stays
// 16x16x32 (6 m-tiles of 32 don't map to 8 waves without L2/LDS blowup).
// Epilogue and LDS footprint (128 x 264 bf16, 2 blocks/CU) unchanged.

typedef __bf16 bf16x8 __attribute__((ext_vector_type(8)));
typedef __bf16 bf16x4v __attribute__((ext_vector_type(4)));
typedef float  f32x16 __attribute__((ext_vector_type(16)));
typedef float  f32x8 __attribute__((ext_vector_type(8)));
typedef float  f32x4 __attribute__((ext_vector_type(4)));
typedef float  f32x2 __attribute__((ext_vector_type(2)));

#define MFMA16(a,b,c) __builtin_amdgcn_mfma_f32_16x16x32_bf16((a),(b),(c),0,0,0)
#define MFMA32(a,b,c) __builtin_amdgcn_mfma_f32_32x32x16_bf16((a),(b),(c),0,0,0)

// sw layout (bf16 elems):
//   W0' : 32x32 A-frags, 1 ks (K=16, real K=8) x 8 mt x 512   = 4096
//   W1' : 32x32 A-frags, 16 ks x 8 mt x 512                   = 65536
//   Wout': 16x16 A-frags (unchanged), 8 kb x 12 nt x 512      = 49152
//   bout'[192] floats (*log2e) after SW_TOTAL
#define SW_W1_OFF 4096
#define SW_WO_OFF 69632
#define SW_TOTAL  118784

#define ROWS    128
#define HSTRIDE 264         // h row stride in bf16 (528 B: 16B-aligned)
#define LOG2E   1.44269504f
#define LN2     0.69314718f
#define SPCONST 0.7806568f      // log(exp(1-1e-4)-1) * log2e
#define ZSENT  (-0.00015680f)   // raw-z sentinel whose softplus-chain -> d = 1

__global__ void prep_kernel(const float* __restrict__ W0,
                            const float* __restrict__ W1,
                            const float* __restrict__ Wout,
                            const float* __restrict__ bout,
                            __bf16* __restrict__ sw)
{
  int i = blockIdx.x * 256 + threadIdx.x;
  if (i >= SW_TOTAL + 192) return;
  if (i >= SW_TOTAL){                      // bout'[192] remap (float, *log2e)
    int np = i - SW_TOTAL;
    int t = np / 24, p = np % 24;
    float* boutp = (float*)(sw + SW_TOTAL);
    boutp[np] = (p < 23) ? bout[t*23 + p] * LOG2E : 0.f;
    return;
  }
  if (i < SW_WO_OFF){
    // 32x32x16 A-fragment pack for W0 / W1: lane l holds A[m=l&31][k=(l>>5)*8+j]
    const float* src; int K; int li;
    if (i < SW_W1_OFF){ src = W0; K = 8;   li = i; }
    else              { src = W1; K = 256; li = i - SW_W1_OFF; }
    int j    = li & 7;
    int l    = (li >> 3) & 63;
    int rest = li >> 9;
    int mt   = rest & 7;
    int ks   = rest >> 3;
    int k = ks*16 + ((l >> 5) << 3) + j;
    int n = mt*32 + (l & 31);
    sw[i] = (__bf16)((k < K) ? src[k*256 + n] : 0.f);
  } else {
    // Wout': 16x16x32 A-fragments over 192 padded cols (24-slot, p==23 zero)
    int li   = i - SW_WO_OFF;
    int j    = li & 7;
    int l    = (li >> 3) & 63;
    int rest = li >> 9;
    int nt   = rest % 12;
    int kb   = rest / 12;
    int k = kb*32 + ((l >> 4) << 3) + j;
    int n = nt*16 + (l & 15);
    int t = n / 24, p = n % 24;
    sw[i] = (__bf16)((p < 23) ? Wout[k*184 + t*23 + p] * LOG2E : 0.f);
  }
}

// relu + cvt of one reg-quad of a 32x32 accumulator (bias already inside acc)
__device__ __forceinline__ bf16x4v reluq(const f32x16& c, int Q){
  f32x4 s;
  s[0] = c[4*Q+0]; s[1] = c[4*Q+1]; s[2] = c[4*Q+2]; s[3] = c[4*Q+3];
  const f32x4 z = {0.f, 0.f, 0.f, 0.f};
  s = __builtin_elementwise_max(s, z);
  return __builtin_convertvector(s, bf16x4v);   // v_cvt_pk_bf16_f32 x2
}

__global__ __launch_bounds__(512, 4)
void fused_kernel(const float* __restrict__ x,
                  const float* __restrict__ b0v,
                  const float* __restrict__ b1v,
                  const __bf16* __restrict__ sw,
                  float* __restrict__ out,
                  int nrows)
{
  // ONE aliased buffer: h1 -> h2 (in place) -> raw. 128 x 264 bf16 = 66 KB.
  __shared__ __align__(16) unsigned char smem[ROWS * HSTRIDE * 2];
  __bf16* hbuf = (__bf16*)smem;
  __bf16* rawb = hbuf;

  const int tid  = threadIdx.x;
  const int wave = tid >> 6;
  const int lane = tid & 63;
  const int quad = lane >> 4;
  const int l16  = lane & 15;
  const int l32  = lane & 31;
  const int hi   = lane >> 5;
  const int row0 = blockIdx.x * ROWS;

  const __bf16* swW1 = sw + SW_W1_OFF;
  const __bf16* swWo = sw + SW_WO_OFF;
  const float* boutp = (const float*)(sw + SW_TOTAL);

  // ---- x2 passthrough: 2 float4 per row on 256 threads (independent)
  if (tid < 2*ROWS){
    int r = tid >> 1, hf = tid & 1;
    long g = (long)row0 + r;
    *(float4*)(out + g*16 + 8 + hf*4) = *(const float4*)(x + g*16 + 8 + hf*4);
  }

  // ---- GEMM1 (32x32x16, transposed): h1[b][m] = relu(W0'^T x2 + b0)
  // wave = m-tile (8 tiles of 32), all 4 batch tiles; K=16 (real 8).
  {
    bf16x8 bfr[4];
    #pragma unroll
    for (int bt = 0; bt < 4; bt++){
      bf16x8 b = {};                       // k = hi*8+j; only hi==0 (k<8) real
      if (hi == 0){
        const float* xp = x + (long)(row0 + bt*32 + l32)*16 + 8;
        float4 u = *(const float4*)xp;
        float4 v = *(const float4*)(xp + 4);
        f32x8 xf; xf[0]=u.x; xf[1]=u.y; xf[2]=u.z; xf[3]=u.w;
                  xf[4]=v.x; xf[5]=v.y; xf[6]=v.z; xf[7]=v.w;
        b = __builtin_convertvector(xf, bf16x8);
      }
      bfr[bt] = b;
    }
    bf16x8 a = *(const bf16x8*)(sw + (wave*64 + lane)*8);
    f32x16 ci;                             // bias in C-operand: m = 8Q+4hi+r
    #pragma unroll
    for (int Q = 0; Q < 4; Q++){
      float4 bq = *(const float4*)(b0v + wave*32 + Q*8 + hi*4);
      ci[4*Q+0]=bq.x; ci[4*Q+1]=bq.y; ci[4*Q+2]=bq.z; ci[4*Q+3]=bq.w;
    }
    #pragma unroll
    for (int bt = 0; bt < 4; bt++){
      f32x16 c = MFMA32(a, bfr[bt], ci);
      __bf16* hp = hbuf + (bt*32 + l32)*HSTRIDE + wave*32 + hi*4;
      #pragma unroll
      for (int Q = 0; Q < 4; Q++)
        *(bf16x4v*)(hp + Q*8) = reluq(c, Q);
    }
  }
  __syncthreads();

  // ---- GEMM2 (32x32x16, transposed): h2[b][m] = relu(W1'^T h1 + b1)
  // wave = (mp: 4 m-pairs) x (bh: 2 batch halves); acc[2][2] f32x16.
  {
    const int mp = wave >> 1;
    const int bh = wave & 1;
    f32x16 acc[2][2];                      // [mi][bi]
    #pragma unroll
    for (int mi = 0; mi < 2; mi++){
      f32x16 c;
      #pragma unroll
      for (int Q = 0; Q < 4; Q++){
        float4 bq = *(const float4*)(b1v + (mp*2+mi)*32 + Q*8 + hi*4);
        c[4*Q+0]=bq.x; c[4*Q+1]=bq.y; c[4*Q+2]=bq.z; c[4*Q+3]=bq.w;
      }
      acc[mi][0] = c; acc[mi][1] = c;
    }
    #pragma unroll
    for (int ks = 0; ks < 16; ks++){
      bf16x8 hf[2];
      #pragma unroll
      for (int bi = 0; bi < 2; bi++)
        hf[bi] = *(const bf16x8*)(hbuf + ((bh*2+bi)*32 + l32)*HSTRIDE + ks*16 + hi*8);
      #pragma unroll
      for (int mi = 0; mi < 2; mi++){
        bf16x8 a = *(const bf16x8*)(swW1 + ((ks*8 + mp*2 + mi)*64 + lane)*8);
        #pragma unroll
        for (int bi = 0; bi < 2; bi++)
          acc[mi][bi] = MFMA32(a, hf[bi], acc[mi][bi]);
      }
    }
    __syncthreads();
    #pragma unroll
    for (int mi = 0; mi < 2; mi++)
      #pragma unroll
      for (int bi = 0; bi < 2; bi++){
        __bf16* hp = hbuf + ((bh*2+bi)*32 + l32)*HSTRIDE + (mp*2+mi)*32 + hi*4;
        #pragma unroll
        for (int Q = 0; Q < 4; Q++)
          *(bf16x4v*)(hp + Q*8) = reluq(acc[mi][bi], Q);
      }
  }
  __syncthreads();

  // ---- GEMM3 (16x16x32, 192 padded cols): raw2[b][n'] = Wout'^T h2 + bout'
  // wave = (nc: 3 n'-tiles) x (mh half of batch: 4 tiles); bias in C-operand.
  {
    const int nc = wave & 3;
    const int mh = wave >> 2;
    f32x4 acc[4][3];                       // [bt][mi]
    #pragma unroll
    for (int mi = 0; mi < 3; mi++){
      float4 bb = *(const float4*)(boutp + (nc*3+mi)*16 + quad*4);
      f32x4 c; c[0]=bb.x; c[1]=bb.y; c[2]=bb.z; c[3]=bb.w;
      #pragma unroll
      for (int bt = 0; bt < 4; bt++) acc[bt][mi] = c;
    }
    #pragma unroll
    for (int kb = 0; kb < 8; kb++){
      bf16x8 hf[4];
      #pragma unroll
      for (int bt = 0; bt < 4; bt++)
        hf[bt] = *(const bf16x8*)(hbuf + ((mh*4+bt)*16 + l16)*HSTRIDE + kb*32 + quad*8);
      #pragma unroll
      for (int mi = 0; mi < 3; mi++){
        bf16x8 a = *(const bf16x8*)(swWo + ((kb*12 + nc*3 + mi)*64 + lane)*8);
        #pragma unroll
        for (int bt = 0; bt < 4; bt++)
          acc[bt][mi] = MFMA16(a, hf[bt], acc[bt][mi]);
      }
    }
    __syncthreads();
    #pragma unroll
    for (int mi = 0; mi < 3; mi++){
      int mt = nc*3 + mi;
      #pragma unroll
      for (int bt = 0; bt < 4; bt++){
        int row = (mh*4+bt)*16 + l16;
        *(bf16x4v*)(rawb + row*HSTRIDE + mt*16 + quad*4) =
            __builtin_convertvector(acc[bt][mi], bf16x4v);
      }
    }
  }
  __syncthreads();

  // ---- RQ spline epilogue: 1024 tasks, 2/thread; ldet via shfl_xor
  float ldv[2];
  #pragma unroll
  for (int pp = 0; pp < 2; pp++){
    int p   = tid + pp*512;
    int row = p >> 3;
    int t   = p & 7;
    long gr = row0 + row;
    float xv = x[gr*16 + t];

    const __bf16* rr = rawb + row*HSTRIDE + t*24;   // 48B slots, b128-aligned
    bf16x8 v0 = *(const bf16x8*)(rr);
    bf16x8 v1 = *(const bf16x8*)(rr + 8);
    bf16x8 v2 = *(const bf16x8*)(rr + 16);

    // raw2 already in log2-units: 2^raw2 = e^raw exactly
    f32x2 ewh[8];
    f32x2 sum = {0.f, 0.f};
    #pragma unroll
    for (int i=0;i<8;i++){
      f32x2 e;
      e[0] = __builtin_amdgcn_exp2f((float)v0[i]);
      e[1] = __builtin_amdgcn_exp2f((float)v1[i]);
      ewh[i] = e; sum += e;
    }
    f32x2 scale;
    scale[0] = 1.9984f * __builtin_amdgcn_rcpf(sum[0]);
    scale[1] = 1.9984f * __builtin_amdgcn_rcpf(sum[1]);
    const f32x2 off2 = {2e-4f, 2e-4f};

    bool msk = (xv <= -0.999f) || (xv >= 0.999f);
    float xin = msk ? 0.f : xv;

    // packed scan; sentinel-select raw z for the two needed derivatives
    f32x2 whi = ewh[0]*scale + off2;
    f32x2 ec; ec[0] = -1.f + whi[0]; ec[1] = -1.f + whi[1];
    f32x2 xyk = {-1.f, -1.f};
    f32x2 whk = whi;
    float zk = ZSENT, zk1 = (float)v2[0];
    #pragma unroll
    for (int i=1;i<8;i++){
      whi = ewh[i]*scale + off2;
      bool le = (ec[0] <= xin);
      xyk = le ? ec : xyk;
      whk = le ? whi : whk;
      zk  = le ? (float)v2[i-1] : zk;
      zk1 = le ? ((i==7) ? ZSENT : (float)v2[i]) : zk1;
      ec += whi;
    }

    // softplus (base-2) only for the two selected derivatives
    float za = zk + SPCONST, zb = zk1 + SPCONST;
    float dk  = (fmaxf(za,0.f) + __builtin_amdgcn_logf(1.f + __builtin_amdgcn_exp2f(-fabsf(za))))*LN2 + 1e-4f;
    float dk1 = (fmaxf(zb,0.f) + __builtin_amdgcn_logf(1.f + __builtin_amdgcn_exp2f(-fabsf(zb))))*LN2 + 1e-4f;

    float rwk = __builtin_amdgcn_rcpf(whk[0]);
    float sk  = whk[1] * rwk;
    float eps = (xin - xyk[0]) * rwk;
    float om  = 1.f - eps;
    float et  = eps * om;
    float e2  = eps * eps;
    float beta  = sk + (dk1 + dk - 2.f*sk) * et;
    float rb    = __builtin_amdgcn_rcpf(beta);
    float alpha = whk[1] * (sk*e2 + dk*et);
    float yv  = msk ? xv : (xyk[1] + alpha * rb);
    float num = dk1*e2 + 2.f*sk*et + dk*om*om;
    float ld  = msk ? 0.f : __builtin_amdgcn_logf(sk*sk*num*rb*rb) * LN2;

    out[gr*16 + t] = yv;
    ldv[pp] = ld;
  }

  // per-row logdet: 8 t-lanes are adjacent -> 3-step shfl_xor reduction
  float s0 = ldv[0], s1 = ldv[1];
  #pragma unroll
  for (int m = 1; m < 8; m <<= 1){
    s0 += __shfl_xor(s0, m);
    s1 += __shfl_xor(s1, m);
  }
  if ((lane & 7) == 0){
    int r = tid >> 3;                    // 0..63
    out[(long)nrows*16 + row0 + r]      = s0;
    out[(long)nrows*16 + row0 + r + 64] = s1;
  }
}

extern "C" void kernel_launch(void* const* d_in, const int* in_sizes, int n_in,
                              void* d_out, int out_size, void* d_ws, size_t ws_size,
                              hipStream_t stream)
{
  const float* x    = (const float*)d_in[0];
  const float* W0   = (const float*)d_in[1];
  const float* b0   = (const float*)d_in[2];
  const float* W1   = (const float*)d_in[3];
  const float* b1   = (const float*)d_in[4];
  const float* Wout = (const float*)d_in[5];
  const float* bout = (const float*)d_in[6];
  float* out = (float*)d_out;
  __bf16* sw = (__bf16*)d_ws;

  int nrows = in_sizes[0] / 16;          // 524288
  int ntiles = nrows / ROWS;             // 4096

  prep_kernel<<<(SW_TOTAL + 192 + 255)/256, 256, 0, stream>>>(W0, W1, Wout, bout, sw);
  fused_kernel<<<ntiles, 512, 0, stream>>>(x, b0, b1, sw, out, nrows);
}